// Round 11
// baseline (574.951 us; speedup 1.0000x reference)
//
#include <hip/hip_runtime.h>

// ---------------- types / helpers ----------------
typedef __attribute__((ext_vector_type(8))) _Float16 half8;
typedef __attribute__((ext_vector_type(4))) _Float16 half4;
typedef __attribute__((ext_vector_type(4))) float float4v;
typedef __attribute__((ext_vector_type(2))) float float2v;

__device__ __forceinline__ float4v mfma16h(half8 a, half8 b, float4v c) {
  return __builtin_amdgcn_mfma_f32_16x16x32_f16(a, b, c, 0, 0, 0);
}

__device__ __forceinline__ half8 cat44h(half4 a, half4 b) {
  half8 r;
  r[0]=a[0]; r[1]=a[1]; r[2]=a[2]; r[3]=a[3];
  r[4]=b[0]; r[5]=b[1]; r[6]=b[2]; r[7]=b[3];
  return r;
}

__device__ __forceinline__ void split_f16(float x, _Float16& hi, _Float16& lo) {
  hi = (_Float16)x;                 // RNE
  lo = (_Float16)(x - (float)hi);
}

#define KLOG2E 1.442695041f
__device__ __forceinline__ float fast_tanh(float x) {
  float z = __builtin_amdgcn_exp2f(2.f * KLOG2E * x);
  return 1.f - 2.f * __builtin_amdgcn_rcpf(1.f + z);
}

// sizes: B=16 L=96 H=150 4H=600(pad 640) EMB=150(pad 160) 2H=300(pad 320)
// fragment slot formula (same for A and B operands; permutation cancels):
//   k(lane,e) = 32*kc + 16*(e>>2) + 4*(lane>>4) + (e&3)
// GATE-QUAD permutation: tile nt = jg*4 + gate, source row g = gate*150 + jg*16 + lrow.
// GATE-SCALE folding: rows pre-scaled by (-log2e) for i,f,o and (+2log2e) for g.
// SCAN (8 waves, balanced): wave w owns quad w in-reg (j=16w+lrow) + one tile of
//   quads 8,9 (tile 32+w: gate w&3, jg=8+(w>>2)) redistributed via LDS gX.
// PRE layout: [dir][t][sc_tid(512)][20]: floats 0..15 = own quad (gate*4+jj),
//   16..19 = extra tile C-in. X layout (PADDED) as before.

// ---------------- prep: weight fragments + embedding gather (fused) ----------
__global__ void prep_kernel(
    const float* __restrict__ Wih0,   // [2][600][150]
    const float* __restrict__ WihR,   // [3][2][600][300]
    const float* __restrict__ Whh,    // [4][2][600][150]
    const float* __restrict__ bih,    // [4][2][600]
    const float* __restrict__ bhh,    // [4][2][600]
    const float* __restrict__ w1m,    // [100][600]
    const float* __restrict__ b1v,    // [100]
    const int* __restrict__ widx, const int* __restrict__ pidx,
    const float* __restrict__ wemb, const float* __restrict__ temb,
    _Float16* __restrict__ whh_f,
    _Float16* __restrict__ wih_f,
    _Float16* __restrict__ wpr_f,
    float* __restrict__ bsum, float* __restrict__ b1cat,
    _Float16* __restrict__ xa)
{
  const int N_whh  = 8 * 40 * 5 * 512;   // 819200
  const int N_wih0 = 2 * 40 * 5 * 512;   // 204800
  const int N_wihr = 6 * 40 * 10 * 512;  // 1228800
  const int N_wpr  = 16 * 10 * 512;      // 81920
  const int N_bs   = 8 * 640;            // 5120
  const int N_emb  = 1536 * 320;         // 491520
  const int total  = N_whh + N_wih0 + N_wihr + N_wpr + N_bs + 256 + N_emb;
  for (int i = blockIdx.x * blockDim.x + threadIdx.x; i < total;
       i += gridDim.x * blockDim.x) {
    int idx = i;
    if (idx < N_whh) {
      int e = idx & 7, lane = (idx >> 3) & 63, r = idx >> 9;
      int kc = r % 5; r /= 5; int nt = r % 40; int ld = r / 40;
      int jrow = (nt >> 2) * 16 + (lane & 15);
      int g = (nt & 3) * 150 + jrow;
      int k = 32 * kc + 16 * (e >> 2) + 4 * (lane >> 4) + (e & 3);
      float v = (jrow < 150 && k < 150) ? Whh[((size_t)ld * 600 + g) * 150 + k] : 0.f;
      v *= ((nt & 3) == 2) ? (2.f * KLOG2E) : (-KLOG2E);
      whh_f[idx] = (_Float16)v;
      continue;
    }
    idx -= N_whh;
    if (idx < N_wih0) {
      int e = idx & 7, lane = (idx >> 3) & 63, r = idx >> 9;
      int kc = r % 5; r /= 5; int nt = r % 40; int dir = r / 40;
      int jrow = (nt >> 2) * 16 + (lane & 15);
      int g = (nt & 3) * 150 + jrow;
      int k = 32 * kc + 16 * (e >> 2) + 4 * (lane >> 4) + (e & 3);
      float v = (jrow < 150 && k < 150) ? Wih0[((size_t)dir * 600 + g) * 150 + k] : 0.f;
      v *= ((nt & 3) == 2) ? (2.f * KLOG2E) : (-KLOG2E);
      wih_f[idx] = (_Float16)v;
      continue;
    }
    idx -= N_wih0;
    if (idx < N_wihr) {
      int e = idx & 7, lane = (idx >> 3) & 63, r = idx >> 9;
      int kc = r % 10; r /= 10; int nt = r % 40; int ld = r / 40;
      int jrow = (nt >> 2) * 16 + (lane & 15);
      int g = (nt & 3) * 150 + jrow;
      int k = 32 * kc + 16 * (e >> 2) + 4 * (lane >> 4) + (e & 3);
      // padded-X remap: x cols [0,150)=dir0 h, [160,310)=dir1 h, rest pad(zero)
      int ks = (k < 150) ? k : ((k >= 160 && k < 310) ? (k - 10) : -1);
      float v = (jrow < 150 && ks >= 0) ? WihR[((size_t)ld * 600 + g) * 300 + ks] : 0.f;
      v *= ((nt & 3) == 2) ? (2.f * KLOG2E) : (-KLOG2E);
      wih_f[N_wih0 + idx] = (_Float16)v;
      continue;
    }
    idx -= N_wihr;
    if (idx < N_wpr) {
      int e = idx & 7, lane = (idx >> 3) & 63, r = idx >> 9;
      int kc = r % 10; int nt = r / 10;
      int ko = 16 * nt + (lane & 15);
      int k = 32 * kc + 16 * (e >> 2) + 4 * (lane >> 4) + (e & 3);
      int ks = (k < 150) ? k : ((k >= 160 && k < 310) ? (k - 10) : -1);
      float v = 0.f;
      if (ks >= 0) {
        if (ko < 100) v = w1m[(size_t)ko * 600 + ks];
        else if (ko < 200) v = w1m[(size_t)(ko - 100) * 600 + 300 + ks];
      }
      wpr_f[idx] = (_Float16)v;
      continue;
    }
    idx -= N_wpr;
    if (idx < N_bs) {
      int ld = idx / 640, gp = idx - 640 * ld;
      int nt = gp >> 4, lrow = gp & 15;
      int jrow = (nt >> 2) * 16 + lrow;
      int g = (nt & 3) * 150 + jrow;
      float v = (jrow < 150) ? bih[ld * 600 + g] + bhh[ld * 600 + g] : 0.f;
      v *= ((nt & 3) == 2) ? (2.f * KLOG2E) : (-KLOG2E);
      bsum[idx] = v;
      continue;
    }
    idx -= N_bs;
    if (idx < 256) {
      b1cat[idx] = (idx < 100) ? b1v[idx] : ((idx < 200) ? b1v[idx - 100] : 0.f);
      continue;
    }
    idx -= 256;
    // embedding gather: idx over [1536][320] (cols >=150 zero)
    {
      int row = idx / 320, j = idx - 320 * row;
      int b = row & 15, t = row >> 4;
      float v = 0.f;
      if (j < 100) v = wemb[(size_t)widx[b * 96 + t] * 100 + j];
      else if (j < 150) v = temb[(size_t)pidx[b * 96 + t] * 50 + (j - 100)];
      xa[idx] = (_Float16)v;
    }
  }
}

// ---------------- pre-GEMM: writes scan-thread-ordered PRE chunks (20 floats) ------
template <int KC>
__global__ __launch_bounds__(512) void pregemm_kernel(
    const _Float16* __restrict__ x_h,
    const _Float16* __restrict__ wih_f,
    const float* __restrict__ bsum_l,
    float* __restrict__ pre)            // [2][96][512][20]
{
  const int t = blockIdx.x, dir = blockIdx.y;
  const int tid = threadIdx.x, wv = tid >> 6, lane = tid & 63;
  const int lrow = lane & 15, lgrp = lane >> 4;
  const _Float16* wf = wih_f + (size_t)dir * 40 * KC * 512;
  float4v acc[5];
#pragma unroll
  for (int tt = 0; tt < 5; ++tt) acc[tt] = (float4v){0.f, 0.f, 0.f, 0.f};
  const size_t arow = ((size_t)t * 16 + lrow) * 320;
#pragma unroll
  for (int kc = 0; kc < KC; ++kc) {
    int co = 32 * kc + 4 * lgrp;
    half8 ah = cat44h(*(const half4*)(x_h + arow + co),
                      *(const half4*)(x_h + arow + co + 16));
#pragma unroll
    for (int tt = 0; tt < 5; ++tt) {
      int nt = 5 * wv + tt;
      const size_t wo = ((size_t)(nt * KC + kc) * 64 + lane) * 8;
      half8 bw = *(const half8*)(wf + wo);
      acc[tt] = mfma16h(ah, bw, acc[tt]);
    }
  }
  float* po = pre + (size_t)(dir * 96 + t) * 10240;
  const float* bs = bsum_l + dir * 640;
#pragma unroll
  for (int tt = 0; tt < 5; ++tt) {
    int nt = 5 * wv + tt;
    float bv = bs[16 * nt + lrow];
    float4v v;
#pragma unroll
    for (int jj = 0; jj < 4; ++jj) v[jj] = acc[tt][jj] + bv;
    int sc_tid, slot;
    if (nt < 32) { sc_tid = (nt >> 2) * 64 + lgrp * 16 + lrow; slot = (nt & 3) * 4; }
    else         { sc_tid = (nt - 32) * 64 + lgrp * 16 + lrow; slot = 16; }
    *(float4v*)(po + (size_t)sc_tid * 20 + slot) = v;
  }
}

// ---------------- sequential LSTM scan: 8 balanced waves ----------------
// Wave w: quad w in-reg (4 tiles) + extra tile 32+w (gate w&3 of jg=8+(w>>2)).
// Extra-quad gates redistributed via LDS gX; each thread finishes ONE extra cell
// (b=tid>>5, j'=128+(tid&31)). Two counted barriers/step.
__global__ __launch_bounds__(512, 1) void scan_kernel(
    const float* __restrict__ pre,                 // [2][96][512][20]
    const _Float16* __restrict__ whh_f,
    _Float16* __restrict__ xo,                     // [1536][320] padded layout
    int layer)
{
  const int dir = blockIdx.x;
  const int tid = threadIdx.x, wv = tid >> 6, lane = tid & 63;
  const int lrow = lane & 15, lgrp = lane >> 4;

  // h in MFMA A-fragment order, row stride 172 (conflict-free ds_read_b128)
  __shared__ __align__(16) _Float16 hb[2][16 * 172];
  __shared__ float gXl[16 * 132];                  // [b(stride132)][gate*32+col]

  for (int i = tid; i < 2 * 16 * 172; i += 512)
    (&hb[0][0])[i] = (_Float16)0.f;

  // Whh fragments: own quad (4 tiles x 5 kc) + extra tile (5 kc) per wave
  const _Float16* b_base = whh_f + (size_t)(layer * 2 + dir) * 40 * 5 * 512;
  half8 Bw[4][5], BwX[5];
#pragma unroll
  for (int tt = 0; tt < 4; ++tt)
#pragma unroll
    for (int kc = 0; kc < 5; ++kc) {
      size_t o = ((size_t)((4 * wv + tt) * 5 + kc) * 64 + lane) * 8;
      Bw[tt][kc] = *(const half8*)(b_base + o);
    }
#pragma unroll
  for (int kc = 0; kc < 5; ++kc) {
    size_t o = ((size_t)((32 + wv) * 5 + kc) * 64 + lane) * 8;
    BwX[kc] = *(const half8*)(b_base + o);
  }

  float2v cst01 = {0.f, 0.f}, cst23 = {0.f, 0.f};
  float cstX = 0.f;
  const int j = 16 * wv + lrow;          // own cell column (<=127, always real)
  const int kcj = j >> 5, wj = j & 31;
  const int hoff = kcj * 32 + ((wj >> 2) & 3) * 8 + (wj >> 4) * 4 + (wj & 3);
  // extra cell: (bX, j' = 128 + jjX)
  const int bX = tid >> 5, jjX = tid & 31;
  const int hoffX = 128 + ((jjX >> 2) & 3) * 8 + (jjX >> 4) * 4 + (jjX & 3);
  const int gxw = (wv & 3) * 32 + 16 * (wv >> 2) + lrow;  // gX write col+gate

  const int t0 = dir ? 95 : 0;
  const long pincv = dir ? -10240 : 10240;         // floats per t step
  const long xinc = dir ? -(16 * 320) : (16 * 320);
  const float* pc = pre + (size_t)(dir * 96 + t0) * 10240 + (size_t)tid * 20;
  _Float16* xop  = xo + ((size_t)t0 * 16 + 4 * lgrp) * 320 + dir * 160 + j;
  _Float16* xopX = xo + ((size_t)t0 * 16 + bX) * 320 + dir * 160 + 128 + jjX;

  float4v pfA[5], pfB[5];
#pragma unroll
  for (int i = 0; i < 5; ++i) pfA[i] = *(const float4v*)(pc + 4 * i);
  pc += pincv;
#pragma unroll
  for (int i = 0; i < 5; ++i) pfB[i] = *(const float4v*)(pc + 4 * i);
  pc += pincv;

  // per-parity store-source registers (keep-alive pins liveness ~2 steps)
  _Float16 hsA0 = 0, hsA1 = 0, hsA2 = 0, hsA3 = 0, hsA4 = 0;
  _Float16 hsB0 = 0, hsB1 = 0, hsB2 = 0, hsB3 = 0, hsB4 = 0;
  __syncthreads();

#define GATE_PAIR(PF, J0, J1, CST, HVO)                                   \
  {                                                                       \
    float2v zi = {__builtin_amdgcn_exp2f(PF[0][J0]),                      \
                  __builtin_amdgcn_exp2f(PF[0][J1])};                     \
    float2v zf = {__builtin_amdgcn_exp2f(PF[1][J0]),                      \
                  __builtin_amdgcn_exp2f(PF[1][J1])};                     \
    float2v zg = {__builtin_amdgcn_exp2f(PF[2][J0]),                      \
                  __builtin_amdgcn_exp2f(PF[2][J1])};                     \
    float2v zo = {__builtin_amdgcn_exp2f(PF[3][J0]),                      \
                  __builtin_amdgcn_exp2f(PF[3][J1])};                     \
    float2v tq = (1.f + zi) * (zg + 1.f);                                 \
    float2v fq = 1.f + zf;                                                \
    float2v Dq = tq * fq;                                                 \
    float2v Nq = CST * tq + (zg - 1.f) * fq;                              \
    float rP = __builtin_amdgcn_rcpf(Dq[0] * Dq[1]);                      \
    float2v Dsw = __builtin_shufflevector(Dq, Dq, 1, 0);                  \
    float2v cv = Nq * rP * Dsw;                                           \
    CST = cv;                                                             \
    float2v arg = (2.f * KLOG2E) * cv;                                    \
    float2v zc = {__builtin_amdgcn_exp2f(arg[0]),                         \
                  __builtin_amdgcn_exp2f(arg[1])};                        \
    float2v Eq = (1.f + zo) * (zc + 1.f);                                 \
    float rE = __builtin_amdgcn_rcpf(Eq[0] * Eq[1]);                      \
    float2v Esw = __builtin_shufflevector(Eq, Eq, 1, 0);                  \
    HVO = (zc - 1.f) * rE * Esw;                                          \
  }

#define SCAN_STEP(PF, H0, H1, H2, H3, H4, O0, O1, O2, O3, O4, HIN, HOUT)  \
  {                                                                       \
    asm volatile("" :: "v"(O0), "v"(O1), "v"(O2), "v"(O3), "v"(O4));      \
    __builtin_amdgcn_s_setprio(1);                                        \
    _Pragma("unroll")                                                     \
    for (int kc = 0; kc < 5; ++kc) {                                      \
      const int ao = lrow * 172 + kc * 32 + lgrp * 8;                     \
      half8 ah = *(const half8*)((HIN) + ao);                             \
      PF[4] = mfma16h(ah, BwX[kc], PF[4]);                                \
      _Pragma("unroll")                                                   \
      for (int tt = 0; tt < 4; ++tt)                                      \
        PF[tt] = mfma16h(ah, Bw[tt][kc], PF[tt]);                         \
    }                                                                     \
    __builtin_amdgcn_s_setprio(0);                                        \
    _Pragma("unroll")                                                     \
    for (int jj = 0; jj < 4; ++jj)                                        \
      gXl[(4 * lgrp + jj) * 132 + gxw] = PF[4][jj];                       \
    asm volatile("s_waitcnt lgkmcnt(0)" ::: "memory");                    \
    __builtin_amdgcn_s_barrier();                                         \
    asm volatile("" ::: "memory");                                        \
    float2v hv01, hv23;                                                   \
    GATE_PAIR(PF, 0, 1, cst01, hv01)                                      \
    GATE_PAIR(PF, 2, 3, cst23, hv23)                                      \
    {                                                                     \
      float g0 = gXl[bX * 132 + 0 * 32 + jjX];                            \
      float g1 = gXl[bX * 132 + 1 * 32 + jjX];                            \
      float g2 = gXl[bX * 132 + 2 * 32 + jjX];                            \
      float g3 = gXl[bX * 132 + 3 * 32 + jjX];                            \
      float zi = __builtin_amdgcn_exp2f(g0);                              \
      float zf = __builtin_amdgcn_exp2f(g1);                              \
      float zg = __builtin_amdgcn_exp2f(g2);                              \
      float zo = __builtin_amdgcn_exp2f(g3);                              \
      float tq = (1.f + zi) * (zg + 1.f);                                 \
      float fq = 1.f + zf;                                                \
      float cX = (cstX * tq + (zg - 1.f) * fq) *                          \
                 __builtin_amdgcn_rcpf(tq * fq);                          \
      cstX = cX;                                                          \
      float zc = __builtin_amdgcn_exp2f(2.f * KLOG2E * cX);               \
      float hX = (zc - 1.f) *                                             \
                 __builtin_amdgcn_rcpf((1.f + zo) * (zc + 1.f));          \
      H4 = (_Float16)hX;                                                  \
    }                                                                     \
    H0 = (_Float16)hv01[0];                                               \
    H1 = (_Float16)hv01[1];                                               \
    H2 = (_Float16)hv23[0];                                               \
    H3 = (_Float16)hv23[1];                                               \
    (HOUT)[(4 * lgrp + 0) * 172 + hoff] = H0;                             \
    (HOUT)[(4 * lgrp + 1) * 172 + hoff] = H1;                             \
    (HOUT)[(4 * lgrp + 2) * 172 + hoff] = H2;                             \
    (HOUT)[(4 * lgrp + 3) * 172 + hoff] = H3;                             \
    (HOUT)[bX * 172 + hoffX] = H4;                                        \
    xop[0 * 320] = H0; xop[1 * 320] = H1;                                 \
    xop[2 * 320] = H2; xop[3 * 320] = H3;                                 \
    xopX[0] = H4;                                                         \
    _Pragma("unroll")                                                     \
    for (int i = 0; i < 5; ++i) PF[i] = *(const float4v*)(pc + 4 * i);    \
    pc += pincv;                                                          \
    xop += xinc;                                                          \
    xopX += xinc;                                                         \
    asm volatile("s_waitcnt lgkmcnt(0)" ::: "memory");                    \
    __builtin_amdgcn_s_barrier();                                         \
    asm volatile("" ::: "memory");                                        \
  }

#pragma unroll 1
  for (int s2 = 0; s2 < 48; ++s2) {
    SCAN_STEP(pfA, hsA0, hsA1, hsA2, hsA3, hsA4,
              hsB0, hsB1, hsB2, hsB3, hsB4, hb[0], hb[1]);
    SCAN_STEP(pfB, hsB0, hsB1, hsB2, hsB3, hsB4,
              hsA0, hsA1, hsA2, hsA3, hsA4, hb[1], hb[0]);
  }
#undef SCAN_STEP
#undef GATE_PAIR
}

// ---------------- projection (poly fused in via LDS stage) ----------------
// AD[row][0:100]=A+b1, [100:200]=D
__global__ __launch_bounds__(512) void proj_kernel(
    const _Float16* __restrict__ xi,      // [1536][320] layer-3 output (padded)
    const _Float16* __restrict__ wpr_f,
    const float* __restrict__ b1cat,
    const float* __restrict__ w1, const float* __restrict__ w2,
    const float* __restrict__ w3, const float* __restrict__ w4,
    float* __restrict__ AD)   // [1536][256]
{
  const int t = blockIdx.x;
  const int tid = threadIdx.x, wv = tid >> 6, lane = tid & 63;
  const int lrow = lane & 15, lgrp = lane >> 4;
  __shared__ __align__(16) _Float16 ph[16 * 328];  // stride 328: 2-way conflicts only
  __shared__ __align__(16) _Float16 pl[16 * 328];
  {
    float c1 = w1[0], c2 = w2[0], c3 = w3[0], c4 = w4[0];
    for (int e = tid; e < 16 * 320; e += 512) {
      int row = e / 320, col = e - 320 * row;
      float x = (float)xi[(size_t)t * 5120 + e];
      float p = x * (c1 + x * (c2 + x * (c3 + x * c4)));
      _Float16 h, l; split_f16(p, h, l);
      ph[row * 328 + col] = h; pl[row * 328 + col] = l;
    }
  }
  __syncthreads();
  float4v acc[2] = {{0.f, 0.f, 0.f, 0.f}, {0.f, 0.f, 0.f, 0.f}};
#pragma unroll
  for (int kc = 0; kc < 10; ++kc) {
    int co = lrow * 328 + 32 * kc + 4 * lgrp;
    half8 ah = cat44h(*(const half4*)(ph + co), *(const half4*)(ph + co + 16));
    half8 al = cat44h(*(const half4*)(pl + co), *(const half4*)(pl + co + 16));
#pragma unroll
    for (int tt = 0; tt < 2; ++tt) {
      int nt = 2 * wv + tt;
      size_t wo = ((size_t)(nt * 10 + kc) * 64 + lane) * 8;
      half8 bw = *(const half8*)(wpr_f + wo);
      acc[tt] = mfma16h(ah, bw, acc[tt]);
      acc[tt] = mfma16h(al, bw, acc[tt]);
    }
  }
#pragma unroll
  for (int tt = 0; tt < 2; ++tt) {
    int ko = 16 * (2 * wv + tt) + lrow;
    float bv = b1cat[ko];
#pragma unroll
    for (int jj = 0; jj < 4; ++jj)
      AD[((size_t)t * 16 + 4 * lgrp + jj) * 256 + ko] = acc[tt][jj] + bv;
  }
}

// ---------------- combine: out[lh][b][ld] = b2 + sum_k w2[k]*tanh(A+D) ----------------
__global__ __launch_bounds__(768) void combine_kernel(
    const float* __restrict__ AD, const float* __restrict__ w2v,
    const float* __restrict__ b2v, float* __restrict__ out)
{
  const int bb = blockIdx.x & 15, lt = blockIdx.x >> 4;
  const int tid = threadIdx.x;
  __shared__ float Dl[100 * 97];  // [k][ld], stride 97
  __shared__ float Al[100 * 9];   // [k][lh], stride 9
  __shared__ float w2s[100];
  for (int i = tid; i < 96 * 32; i += 768) {
    int ld = i >> 5, f4 = i & 31;
    if (f4 < 25) {
      float4v v = *(const float4v*)(AD + ((size_t)ld * 16 + bb) * 256 + 100 + 4 * f4);
      int k0 = 4 * f4;
      Dl[(k0 + 0) * 97 + ld] = v[0];
      Dl[(k0 + 1) * 97 + ld] = v[1];
      Dl[(k0 + 2) * 97 + ld] = v[2];
      Dl[(k0 + 3) * 97 + ld] = v[3];
    }
  }
  for (int i = tid; i < 8 * 32; i += 768) {
    int lh = i >> 5, f4 = i & 31;
    if (f4 < 25) {
      int lseq = lt * 8 + lh;
      float4v v = *(const float4v*)(AD + ((size_t)lseq * 16 + bb) * 256 + 4 * f4);
      int k0 = 4 * f4;
      Al[(k0 + 0) * 9 + lh] = v[0];
      Al[(k0 + 1) * 9 + lh] = v[1];
      Al[(k0 + 2) * 9 + lh] = v[2];
      Al[(k0 + 3) * 9 + lh] = v[3];
    }
  }
  if (tid < 100) w2s[tid] = w2v[tid];
  __syncthreads();
  int lh = tid / 96, ld = tid - 96 * lh;
  float s = 0.f;
#pragma unroll 4
  for (int k = 0; k < 100; ++k) {
    float x = Al[k * 9 + lh] + Dl[k * 97 + ld];
    s += w2s[k] * fast_tanh(x);
  }
  out[((size_t)(lt * 8 + lh) * 16 + bb) * 96 + ld] = s + b2v[0];
}

// ---------------- host ----------------
extern "C" void kernel_launch(void* const* d_in, const int* in_sizes, int n_in,
                              void* d_out, int out_size, void* d_ws, size_t ws_size,
                              hipStream_t stream)
{
  const int*   widx = (const int*)d_in[0];
  const int*   pidx = (const int*)d_in[1];
  const float* wemb = (const float*)d_in[3];
  const float* temb = (const float*)d_in[4];
  const float* Wih0 = (const float*)d_in[5];
  const float* WihR = (const float*)d_in[6];
  const float* Whh  = (const float*)d_in[7];
  const float* bih  = (const float*)d_in[8];
  const float* bhh  = (const float*)d_in[9];
  const float* w1   = (const float*)d_in[10];
  const float* w2   = (const float*)d_in[11];
  const float* w3   = (const float*)d_in[12];
  const float* w4   = (const float*)d_in[13];
  const float* w1m  = (const float*)d_in[14];
  const float* b1v  = (const float*)d_in[15];
  const float* w2m  = (const float*)d_in[16];
  const float* b2v  = (const float*)d_in[17];
  float* out = (float*)d_out;

  char* ws = (char*)d_ws;
  size_t off = 0;
  auto alloc = [&](size_t bytes) -> char* {
    char* p = ws + off;
    off = (off + bytes + 255) & ~(size_t)255;
    return p;
  };
  _Float16* WHH_F = (_Float16*)alloc(819200ull * 2);
  _Float16* WIH_F = (_Float16*)alloc(1433600ull * 2);
  _Float16* WPR_F = (_Float16*)alloc(81920ull * 2);
  float* BSUM = (float*)alloc(5120ull * 4);
  float* B1C  = (float*)alloc(256ull * 4);
  _Float16* XA = (_Float16*)alloc(491520ull * 2);
  _Float16* XB = (_Float16*)alloc(491520ull * 2);
  float* PRE = (float*)alloc(1966080ull * 4);
  float* AD  = (float*)alloc(1536ull * 256 * 4);

  prep_kernel<<<512, 256, 0, stream>>>(Wih0, WihR, Whh, bih, bhh, w1m, b1v,
      widx, pidx, wemb, temb,
      WHH_F, WIH_F, WPR_F, BSUM, B1C, XA);

  for (int layer = 0; layer < 4; ++layer) {
    const _Float16* xin = (layer & 1) ? XB : XA;
    _Float16* xout = (layer & 1) ? XA : XB;
    const float* bsl = BSUM + layer * 2 * 640;
    if (layer == 0) {
      pregemm_kernel<5><<<dim3(96, 2), 512, 0, stream>>>(xin, WIH_F, bsl, PRE);
    } else {
      size_t wo = 204800ull + (size_t)(layer - 1) * 409600ull;
      pregemm_kernel<10><<<dim3(96, 2), 512, 0, stream>>>(xin, WIH_F + wo, bsl, PRE);
    }
    scan_kernel<<<2, 512, 0, stream>>>(PRE, WHH_F, xout, layer);
  }
  // layer-3 output sits in XA; proj (poly fused) -> AD; combine -> out
  proj_kernel<<<96, 512, 0, stream>>>(XA, WPR_F, B1C, w1, w2, w3, w4, AD);
  combine_kernel<<<192, 768, 0, stream>>>(AD, w2m, b2v, out);
}

// Round 12
// 489.747 us; speedup vs baseline: 1.1740x; 1.1740x over previous
//
#include <hip/hip_runtime.h>

// ---------------- types / helpers ----------------
typedef __attribute__((ext_vector_type(8))) _Float16 half8;
typedef __attribute__((ext_vector_type(4))) _Float16 half4;
typedef __attribute__((ext_vector_type(4))) float float4v;
typedef __attribute__((ext_vector_type(2))) float float2v;

__device__ __forceinline__ float4v mfma16h(half8 a, half8 b, float4v c) {
  return __builtin_amdgcn_mfma_f32_16x16x32_f16(a, b, c, 0, 0, 0);
}

__device__ __forceinline__ half8 cat44h(half4 a, half4 b) {
  half8 r;
  r[0]=a[0]; r[1]=a[1]; r[2]=a[2]; r[3]=a[3];
  r[4]=b[0]; r[5]=b[1]; r[6]=b[2]; r[7]=b[3];
  return r;
}

__device__ __forceinline__ void split_f16(float x, _Float16& hi, _Float16& lo) {
  hi = (_Float16)x;                 // RNE
  lo = (_Float16)(x - (float)hi);
}

#define KLOG2E 1.442695041f
__device__ __forceinline__ float fast_tanh(float x) {
  float z = __builtin_amdgcn_exp2f(2.f * KLOG2E * x);
  return 1.f - 2.f * __builtin_amdgcn_rcpf(1.f + z);
}

// sizes: B=16 L=96 H=150 4H=600(pad 640) EMB=150(pad 160) 2H=300(pad 320)
// fragment slot formula (same for A and B operands; permutation cancels):
//   k(lane,e) = 32*kc + 16*(e>>2) + 4*(lane>>4) + (e&3)
// GATE-QUAD permutation: tile nt = jg*4 + gate, source row g = gate*150 + jg*16 + lrow.
// GATE-SCALE folding: rows pre-scaled by (-log2e) for i,f,o and (+2log2e) for g.
// PRE layout: [dir][t][tid(640)][16].
// X layout (PADDED): row=t*16+b, 320 cols: dir0 h at [0,160), dir1 at [160,320);
//   cols 150..159 and 310..319 are pad (zero); weight K columns remapped in prep.

// ---------------- prep: weight fragments + embedding gather (fused) ----------
__global__ void prep_kernel(
    const float* __restrict__ Wih0,   // [2][600][150]
    const float* __restrict__ WihR,   // [3][2][600][300]
    const float* __restrict__ Whh,    // [4][2][600][150]
    const float* __restrict__ bih,    // [4][2][600]
    const float* __restrict__ bhh,    // [4][2][600]
    const float* __restrict__ w1m,    // [100][600]
    const float* __restrict__ b1v,    // [100]
    const int* __restrict__ widx, const int* __restrict__ pidx,
    const float* __restrict__ wemb, const float* __restrict__ temb,
    _Float16* __restrict__ whh_f,
    _Float16* __restrict__ wih_f,
    _Float16* __restrict__ wpr_f,
    float* __restrict__ bsum, float* __restrict__ b1cat,
    _Float16* __restrict__ xa)
{
  const int N_whh  = 8 * 40 * 5 * 512;   // 819200
  const int N_wih0 = 2 * 40 * 5 * 512;   // 204800
  const int N_wihr = 6 * 40 * 10 * 512;  // 1228800
  const int N_wpr  = 16 * 10 * 512;      // 81920
  const int N_bs   = 8 * 640;            // 5120
  const int N_emb  = 1536 * 320;         // 491520
  const int total  = N_whh + N_wih0 + N_wihr + N_wpr + N_bs + 256 + N_emb;
  for (int i = blockIdx.x * blockDim.x + threadIdx.x; i < total;
       i += gridDim.x * blockDim.x) {
    int idx = i;
    if (idx < N_whh) {
      int e = idx & 7, lane = (idx >> 3) & 63, r = idx >> 9;
      int kc = r % 5; r /= 5; int nt = r % 40; int ld = r / 40;
      int jrow = (nt >> 2) * 16 + (lane & 15);
      int g = (nt & 3) * 150 + jrow;
      int k = 32 * kc + 16 * (e >> 2) + 4 * (lane >> 4) + (e & 3);
      float v = (jrow < 150 && k < 150) ? Whh[((size_t)ld * 600 + g) * 150 + k] : 0.f;
      v *= ((nt & 3) == 2) ? (2.f * KLOG2E) : (-KLOG2E);
      whh_f[idx] = (_Float16)v;
      continue;
    }
    idx -= N_whh;
    if (idx < N_wih0) {
      int e = idx & 7, lane = (idx >> 3) & 63, r = idx >> 9;
      int kc = r % 5; r /= 5; int nt = r % 40; int dir = r / 40;
      int jrow = (nt >> 2) * 16 + (lane & 15);
      int g = (nt & 3) * 150 + jrow;
      int k = 32 * kc + 16 * (e >> 2) + 4 * (lane >> 4) + (e & 3);
      float v = (jrow < 150 && k < 150) ? Wih0[((size_t)dir * 600 + g) * 150 + k] : 0.f;
      v *= ((nt & 3) == 2) ? (2.f * KLOG2E) : (-KLOG2E);
      wih_f[idx] = (_Float16)v;
      continue;
    }
    idx -= N_wih0;
    if (idx < N_wihr) {
      int e = idx & 7, lane = (idx >> 3) & 63, r = idx >> 9;
      int kc = r % 10; r /= 10; int nt = r % 40; int ld = r / 40;
      int jrow = (nt >> 2) * 16 + (lane & 15);
      int g = (nt & 3) * 150 + jrow;
      int k = 32 * kc + 16 * (e >> 2) + 4 * (lane >> 4) + (e & 3);
      // padded-X remap: x cols [0,150)=dir0 h, [160,310)=dir1 h, rest pad(zero)
      int ks = (k < 150) ? k : ((k >= 160 && k < 310) ? (k - 10) : -1);
      float v = (jrow < 150 && ks >= 0) ? WihR[((size_t)ld * 600 + g) * 300 + ks] : 0.f;
      v *= ((nt & 3) == 2) ? (2.f * KLOG2E) : (-KLOG2E);
      wih_f[N_wih0 + idx] = (_Float16)v;
      continue;
    }
    idx -= N_wihr;
    if (idx < N_wpr) {
      int e = idx & 7, lane = (idx >> 3) & 63, r = idx >> 9;
      int kc = r % 10; int nt = r / 10;
      int ko = 16 * nt + (lane & 15);
      int k = 32 * kc + 16 * (e >> 2) + 4 * (lane >> 4) + (e & 3);
      int ks = (k < 150) ? k : ((k >= 160 && k < 310) ? (k - 10) : -1);
      float v = 0.f;
      if (ks >= 0) {
        if (ko < 100) v = w1m[(size_t)ko * 600 + ks];
        else if (ko < 200) v = w1m[(size_t)(ko - 100) * 600 + 300 + ks];
      }
      wpr_f[idx] = (_Float16)v;
      continue;
    }
    idx -= N_wpr;
    if (idx < N_bs) {
      int ld = idx / 640, gp = idx - 640 * ld;
      int nt = gp >> 4, lrow = gp & 15;
      int jrow = (nt >> 2) * 16 + lrow;
      int g = (nt & 3) * 150 + jrow;
      float v = (jrow < 150) ? bih[ld * 600 + g] + bhh[ld * 600 + g] : 0.f;
      v *= ((nt & 3) == 2) ? (2.f * KLOG2E) : (-KLOG2E);
      bsum[idx] = v;
      continue;
    }
    idx -= N_bs;
    if (idx < 256) {
      b1cat[idx] = (idx < 100) ? b1v[idx] : ((idx < 200) ? b1v[idx - 100] : 0.f);
      continue;
    }
    idx -= 256;
    // embedding gather: idx over [1536][320] (cols >=150 zero)
    {
      int row = idx / 320, j = idx - 320 * row;
      int b = row & 15, t = row >> 4;
      float v = 0.f;
      if (j < 100) v = wemb[(size_t)widx[b * 96 + t] * 100 + j];
      else if (j < 150) v = temb[(size_t)pidx[b * 96 + t] * 50 + (j - 100)];
      xa[idx] = (_Float16)v;
    }
  }
}

// ---------------- pre-GEMM: writes scan-fragment-ordered PRE chunks ----------------
template <int KC>
__global__ __launch_bounds__(512) void pregemm_kernel(
    const _Float16* __restrict__ x_h,
    const _Float16* __restrict__ wih_f,
    const float* __restrict__ bsum_l,
    float* __restrict__ pre)            // [2][96][640][16]
{
  const int t = blockIdx.x, dir = blockIdx.y;
  const int tid = threadIdx.x, wv = tid >> 6, lane = tid & 63;
  const int lrow = lane & 15, lgrp = lane >> 4;
  const _Float16* wf = wih_f + (size_t)dir * 40 * KC * 512;
  float4v acc[5];
#pragma unroll
  for (int tt = 0; tt < 5; ++tt) acc[tt] = (float4v){0.f, 0.f, 0.f, 0.f};
  const size_t arow = ((size_t)t * 16 + lrow) * 320;
#pragma unroll
  for (int kc = 0; kc < KC; ++kc) {
    int co = 32 * kc + 4 * lgrp;
    half8 ah = cat44h(*(const half4*)(x_h + arow + co),
                      *(const half4*)(x_h + arow + co + 16));
#pragma unroll
    for (int tt = 0; tt < 5; ++tt) {
      int nt = 5 * wv + tt;
      const size_t wo = ((size_t)(nt * KC + kc) * 64 + lane) * 8;
      half8 bw = *(const half8*)(wf + wo);
      acc[tt] = mfma16h(ah, bw, acc[tt]);
    }
  }
  float* po = pre + (size_t)(dir * 96 + t) * 10240;
  const float* bs = bsum_l + dir * 640;
#pragma unroll
  for (int tt = 0; tt < 5; ++tt) {
    int nt = 5 * wv + tt;
    float bv = bs[16 * nt + lrow];
    float4v v;
#pragma unroll
    for (int jj = 0; jj < 4; ++jj) v[jj] = acc[tt][jj] + bv;
    int tid_s = (nt >> 2) * 64 + lgrp * 16 + lrow;   // scan-thread owner
    *(float4v*)(po + (size_t)tid_s * 16 + (nt & 3) * 4) = v;
  }
}

// ---------------- sequential LSTM scan: 10 waves, gates thread-local ----------------
// setprio(1) around MFMA cluster staggers wave completion -> MFMA pipe overlaps
// the trans-heavy state phase across waves. State math packed on float2
// (v_pk_*_f32). Counted barrier; padded xo; store-source regs double-buffered.
__global__ __launch_bounds__(640, 1) void scan_kernel(
    const float* __restrict__ pre,                 // [2][96][640][16]
    const _Float16* __restrict__ whh_f,
    _Float16* __restrict__ xo,                     // [1536][320] padded layout
    int layer)
{
  const int dir = blockIdx.x;
  const int tid = threadIdx.x, wv = tid >> 6, lane = tid & 63;
  const int lrow = lane & 15, lgrp = lane >> 4;

  // h in MFMA A-fragment order, row stride 172 (conflict-free ds_read_b128)
  __shared__ __align__(16) _Float16 hb[2][16 * 172];

  for (int i = tid; i < 2 * 16 * 172; i += 640)
    (&hb[0][0])[i] = (_Float16)0.f;

  // Whh fragments resident: 4 gate-quad tiles x 5 kc per wave (40 VGPR)
  const _Float16* b_base = whh_f + (size_t)(layer * 2 + dir) * 40 * 5 * 512;
  half8 Bw[4][5];
#pragma unroll
  for (int tt = 0; tt < 4; ++tt)
#pragma unroll
    for (int kc = 0; kc < 5; ++kc) {
      size_t o = ((size_t)((4 * wv + tt) * 5 + kc) * 64 + lane) * 8;
      Bw[tt][kc] = *(const half8*)(b_base + o);
    }

  float2v cst01 = {0.f, 0.f}, cst23 = {0.f, 0.f};
  const int j = 16 * wv + lrow;          // this thread's cell column
  const int kcj = j >> 5, wj = j & 31;   // h-fragment slot for (b, j)
  const int hoff = kcj * 32 + ((wj >> 2) & 3) * 8 + (wj >> 4) * 4 + (wj & 3);

  const int t0 = dir ? 95 : 0;
  const long pincv = dir ? -2560 : 2560;           // float4v per t step
  const long xinc = dir ? -(16 * 320) : (16 * 320);
  const float4v* pc = (const float4v*)pre + ((size_t)(dir * 96 + t0) * 640 + tid) * 4;
  _Float16* xop = xo + ((size_t)t0 * 16 + 4 * lgrp) * 320 + dir * 160 + j;

  float4v pfA[4], pfB[4];
#pragma unroll
  for (int i = 0; i < 4; ++i) pfA[i] = pc[i];
  pc += pincv;
#pragma unroll
  for (int i = 0; i < 4; ++i) pfB[i] = pc[i];
  pc += pincv;

  // per-parity store-source registers (keep-alive pins liveness ~2 steps)
  _Float16 hsA0 = 0, hsA1 = 0, hsA2 = 0, hsA3 = 0;
  _Float16 hsB0 = 0, hsB1 = 0, hsB2 = 0, hsB3 = 0;
  __syncthreads();

#define GATE_PAIR(PF, J0, J1, CST, HVO)                                   \
  {                                                                       \
    float2v zi = {__builtin_amdgcn_exp2f(PF[0][J0]),                      \
                  __builtin_amdgcn_exp2f(PF[0][J1])};                     \
    float2v zf = {__builtin_amdgcn_exp2f(PF[1][J0]),                      \
                  __builtin_amdgcn_exp2f(PF[1][J1])};                     \
    float2v zg = {__builtin_amdgcn_exp2f(PF[2][J0]),                      \
                  __builtin_amdgcn_exp2f(PF[2][J1])};                     \
    float2v zo = {__builtin_amdgcn_exp2f(PF[3][J0]),                      \
                  __builtin_amdgcn_exp2f(PF[3][J1])};                     \
    float2v tq = (1.f + zi) * (zg + 1.f);                                 \
    float2v fq = 1.f + zf;                                                \
    float2v Dq = tq * fq;                                                 \
    float2v Nq = CST * tq + (zg - 1.f) * fq;                              \
    float rP = __builtin_amdgcn_rcpf(Dq[0] * Dq[1]);                      \
    float2v Dsw = __builtin_shufflevector(Dq, Dq, 1, 0);                  \
    float2v cv = Nq * rP * Dsw;                                           \
    CST = cv;                                                             \
    float2v arg = (2.f * KLOG2E) * cv;                                    \
    float2v zc = {__builtin_amdgcn_exp2f(arg[0]),                         \
                  __builtin_amdgcn_exp2f(arg[1])};                        \
    float2v Eq = (1.f + zo) * (zc + 1.f);                                 \
    float rE = __builtin_amdgcn_rcpf(Eq[0] * Eq[1]);                      \
    float2v Esw = __builtin_shufflevector(Eq, Eq, 1, 0);                  \
    HVO = (zc - 1.f) * rE * Esw;                                          \
  }

#define SCAN_STEP(PF, H0, H1, H2, H3, O0, O1, O2, O3, HIN, HOUT)          \
  {                                                                       \
    asm volatile("" :: "v"(O0), "v"(O1), "v"(O2), "v"(O3));               \
    __builtin_amdgcn_s_setprio(1);                                        \
    _Pragma("unroll")                                                     \
    for (int kc = 0; kc < 5; ++kc) {                                      \
      const int ao = lrow * 172 + kc * 32 + lgrp * 8;                     \
      half8 ah = *(const half8*)((HIN) + ao);                             \
      _Pragma("unroll")                                                   \
      for (int tt = 0; tt < 4; ++tt)                                      \
        PF[tt] = mfma16h(ah, Bw[tt][kc], PF[tt]);                         \
    }                                                                     \
    __builtin_amdgcn_s_setprio(0);                                        \
    float2v hv01, hv23;                                                   \
    GATE_PAIR(PF, 0, 1, cst01, hv01)                                      \
    GATE_PAIR(PF, 2, 3, cst23, hv23)                                      \
    H0 = (_Float16)hv01[0];                                               \
    H1 = (_Float16)hv01[1];                                               \
    H2 = (_Float16)hv23[0];                                               \
    H3 = (_Float16)hv23[1];                                               \
    (HOUT)[(4 * lgrp + 0) * 172 + hoff] = H0;                             \
    (HOUT)[(4 * lgrp + 1) * 172 + hoff] = H1;                             \
    (HOUT)[(4 * lgrp + 2) * 172 + hoff] = H2;                             \
    (HOUT)[(4 * lgrp + 3) * 172 + hoff] = H3;                             \
    xop[0 * 320] = H0; xop[1 * 320] = H1;                                 \
    xop[2 * 320] = H2; xop[3 * 320] = H3;                                 \
    _Pragma("unroll")                                                     \
    for (int i = 0; i < 4; ++i) PF[i] = pc[i];                            \
    pc += pincv;                                                          \
    xop += xinc;                                                          \
    asm volatile("s_waitcnt lgkmcnt(0)" ::: "memory");                    \
    __builtin_amdgcn_s_barrier();                                         \
  }

#pragma unroll 1
  for (int s2 = 0; s2 < 48; ++s2) {
    SCAN_STEP(pfA, hsA0, hsA1, hsA2, hsA3, hsB0, hsB1, hsB2, hsB3, hb[0], hb[1]);
    SCAN_STEP(pfB, hsB0, hsB1, hsB2, hsB3, hsA0, hsA1, hsA2, hsA3, hb[1], hb[0]);
  }
#undef SCAN_STEP
#undef GATE_PAIR
}

// ---------------- projection (poly fused in via LDS stage) ----------------
// AD[row][0:100]=A+b1, [100:200]=D
__global__ __launch_bounds__(512) void proj_kernel(
    const _Float16* __restrict__ xi,      // [1536][320] layer-3 output (padded)
    const _Float16* __restrict__ wpr_f,
    const float* __restrict__ b1cat,
    const float* __restrict__ w1, const float* __restrict__ w2,
    const float* __restrict__ w3, const float* __restrict__ w4,
    float* __restrict__ AD)   // [1536][256]
{
  const int t = blockIdx.x;
  const int tid = threadIdx.x, wv = tid >> 6, lane = tid & 63;
  const int lrow = lane & 15, lgrp = lane >> 4;
  __shared__ __align__(16) _Float16 ph[16 * 328];  // stride 328: 2-way conflicts only
  __shared__ __align__(16) _Float16 pl[16 * 328];
  {
    float c1 = w1[0], c2 = w2[0], c3 = w3[0], c4 = w4[0];
    for (int e = tid; e < 16 * 320; e += 512) {
      int row = e / 320, col = e - 320 * row;
      float x = (float)xi[(size_t)t * 5120 + e];
      float p = x * (c1 + x * (c2 + x * (c3 + x * c4)));
      _Float16 h, l; split_f16(p, h, l);
      ph[row * 328 + col] = h; pl[row * 328 + col] = l;
    }
  }
  __syncthreads();
  float4v acc[2] = {{0.f, 0.f, 0.f, 0.f}, {0.f, 0.f, 0.f, 0.f}};
#pragma unroll
  for (int kc = 0; kc < 10; ++kc) {
    int co = lrow * 328 + 32 * kc + 4 * lgrp;
    half8 ah = cat44h(*(const half4*)(ph + co), *(const half4*)(ph + co + 16));
    half8 al = cat44h(*(const half4*)(pl + co), *(const half4*)(pl + co + 16));
#pragma unroll
    for (int tt = 0; tt < 2; ++tt) {
      int nt = 2 * wv + tt;
      size_t wo = ((size_t)(nt * 10 + kc) * 64 + lane) * 8;
      half8 bw = *(const half8*)(wpr_f + wo);
      acc[tt] = mfma16h(ah, bw, acc[tt]);
      acc[tt] = mfma16h(al, bw, acc[tt]);
    }
  }
#pragma unroll
  for (int tt = 0; tt < 2; ++tt) {
    int ko = 16 * (2 * wv + tt) + lrow;
    float bv = b1cat[ko];
#pragma unroll
    for (int jj = 0; jj < 4; ++jj)
      AD[((size_t)t * 16 + 4 * lgrp + jj) * 256 + ko] = acc[tt][jj] + bv;
  }
}

// ---------------- combine: out[lh][b][ld] = b2 + sum_k w2[k]*tanh(A+D) ----------------
__global__ __launch_bounds__(768) void combine_kernel(
    const float* __restrict__ AD, const float* __restrict__ w2v,
    const float* __restrict__ b2v, float* __restrict__ out)
{
  const int bb = blockIdx.x & 15, lt = blockIdx.x >> 4;
  const int tid = threadIdx.x;
  __shared__ float Dl[100 * 97];  // [k][ld], stride 97
  __shared__ float Al[100 * 9];   // [k][lh], stride 9
  __shared__ float w2s[100];
  for (int i = tid; i < 96 * 32; i += 768) {
    int ld = i >> 5, f4 = i & 31;
    if (f4 < 25) {
      float4v v = *(const float4v*)(AD + ((size_t)ld * 16 + bb) * 256 + 100 + 4 * f4);
      int k0 = 4 * f4;
      Dl[(k0 + 0) * 97 + ld] = v[0];
      Dl[(k0 + 1) * 97 + ld] = v[1];
      Dl[(k0 + 2) * 97 + ld] = v[2];
      Dl[(k0 + 3) * 97 + ld] = v[3];
    }
  }
  for (int i = tid; i < 8 * 32; i += 768) {
    int lh = i >> 5, f4 = i & 31;
    if (f4 < 25) {
      int lseq = lt * 8 + lh;
      float4v v = *(const float4v*)(AD + ((size_t)lseq * 16 + bb) * 256 + 4 * f4);
      int k0 = 4 * f4;
      Al[(k0 + 0) * 9 + lh] = v[0];
      Al[(k0 + 1) * 9 + lh] = v[1];
      Al[(k0 + 2) * 9 + lh] = v[2];
      Al[(k0 + 3) * 9 + lh] = v[3];
    }
  }
  if (tid < 100) w2s[tid] = w2v[tid];
  __syncthreads();
  int lh = tid / 96, ld = tid - 96 * lh;
  float s = 0.f;
#pragma unroll 4
  for (int k = 0; k < 100; ++k) {
    float x = Al[k * 9 + lh] + Dl[k * 97 + ld];
    s += w2s[k] * fast_tanh(x);
  }
  out[((size_t)(lt * 8 + lh) * 16 + bb) * 96 + ld] = s + b2v[0];
}

// ---------------- host ----------------
extern "C" void kernel_launch(void* const* d_in, const int* in_sizes, int n_in,
                              void* d_out, int out_size, void* d_ws, size_t ws_size,
                              hipStream_t stream)
{
  const int*   widx = (const int*)d_in[0];
  const int*   pidx = (const int*)d_in[1];
  const float* wemb = (const float*)d_in[3];
  const float* temb = (const float*)d_in[4];
  const float* Wih0 = (const float*)d_in[5];
  const float* WihR = (const float*)d_in[6];
  const float* Whh  = (const float*)d_in[7];
  const float* bih  = (const float*)d_in[8];
  const float* bhh  = (const float*)d_in[9];
  const float* w1   = (const float*)d_in[10];
  const float* w2   = (const float*)d_in[11];
  const float* w3   = (const float*)d_in[12];
  const float* w4   = (const float*)d_in[13];
  const float* w1m  = (const float*)d_in[14];
  const float* b1v  = (const float*)d_in[15];
  const float* w2m  = (const float*)d_in[16];
  const float* b2v  = (const float*)d_in[17];
  float* out = (float*)d_out;

  char* ws = (char*)d_ws;
  size_t off = 0;
  auto alloc = [&](size_t bytes) -> char* {
    char* p = ws + off;
    off = (off + bytes + 255) & ~(size_t)255;
    return p;
  };
  _Float16* WHH_F = (_Float16*)alloc(819200ull * 2);
  _Float16* WIH_F = (_Float16*)alloc(1433600ull * 2);
  _Float16* WPR_F = (_Float16*)alloc(81920ull * 2);
  float* BSUM = (float*)alloc(5120ull * 4);
  float* B1C  = (float*)alloc(256ull * 4);
  _Float16* XA = (_Float16*)alloc(491520ull * 2);
  _Float16* XB = (_Float16*)alloc(491520ull * 2);
  float* PRE = (float*)alloc(1966080ull * 4);
  float* AD  = (float*)alloc(1536ull * 256 * 4);

  prep_kernel<<<512, 256, 0, stream>>>(Wih0, WihR, Whh, bih, bhh, w1m, b1v,
      widx, pidx, wemb, temb,
      WHH_F, WIH_F, WPR_F, BSUM, B1C, XA);

  for (int layer = 0; layer < 4; ++layer) {
    const _Float16* xin = (layer & 1) ? XB : XA;
    _Float16* xout = (layer & 1) ? XA : XB;
    const float* bsl = BSUM + layer * 2 * 640;
    if (layer == 0) {
      pregemm_kernel<5><<<dim3(96, 2), 512, 0, stream>>>(xin, WIH_F, bsl, PRE);
    } else {
      size_t wo = 204800ull + (size_t)(layer - 1) * 409600ull;
      pregemm_kernel<10><<<dim3(96, 2), 512, 0, stream>>>(xin, WIH_F + wo, bsl, PRE);
    }
    scan_kernel<<<2, 640, 0, stream>>>(PRE, WHH_F, xout, layer);
  }
  // layer-3 output sits in XA; proj (poly fused) -> AD; combine -> out
  proj_kernel<<<96, 512, 0, stream>>>(XA, WPR_F, B1C, w1, w2, w3, w4, AD);
  combine_kernel<<<192, 768, 0, stream>>>(AD, w2m, b2v, out);
}